// Round 1
// baseline (203.710 us; speedup 1.0000x reference)
//
#include <hip/hip_runtime.h>

// Problem constants (fixed by setup_inputs)
constexpr int kB  = 4;
constexpr int kNp = 8192;
constexpr int kNq = 2048;
constexpr int kC  = 64;   // feature channels
constexpr int kCt = 64;   // t_embed channels
constexpr int kK  = 32;   // max samples per query
constexpr float kR2 = (float)(0.2 * 0.2);   // matches numpy f32(radius*radius)

// ---------------------------------------------------------------------------
// Kernel 1: ball query. One wave (64 lanes) per query. Scans points in chunks
// of 64 in ascending index order; ballot+prefix-popcount assigns the first-K
// in-ball indices to slots; uniform early exit once 32 found.
// ---------------------------------------------------------------------------
__global__ __launch_bounds__(256) void ball_query_kernel(
    const float* __restrict__ coords,   // [B][Np][3]
    const float* __restrict__ queries,  // [B][Nq][3]
    int* __restrict__ idxs)             // [B*Nq][K]
{
    const int wave = (int)((blockIdx.x * blockDim.x + threadIdx.x) >> 6);
    const int lane = threadIdx.x & 63;
    const int w    = threadIdx.x >> 6;          // wave within block (0..3)
    const int b    = wave >> 11;                // / Nq (2048)
    const int q    = wave & (kNq - 1);

    const float qx = queries[(b * kNq + q) * 3 + 0];
    const float qy = queries[(b * kNq + q) * 3 + 1];
    const float qz = queries[(b * kNq + q) * 3 + 2];

    __shared__ int s_idx[4][kK];

    const float* cb = coords + (size_t)b * kNp * 3;
    int cnt = 0;
    for (int base = 0; base < kNp; base += 64) {
        const int p = base + lane;
        const float cx = cb[p * 3 + 0];
        const float cy = cb[p * 3 + 1];
        const float cz = cb[p * 3 + 2];
        // exact f32 per-op arithmetic (no fma contraction) to match numpy ref
        const float dx = __fsub_rn(qx, cx);
        const float dy = __fsub_rn(qy, cy);
        const float dz = __fsub_rn(qz, cz);
        const float d2 = __fadd_rn(__fadd_rn(__fmul_rn(dx, dx), __fmul_rn(dy, dy)),
                                   __fmul_rn(dz, dz));
        const bool in_ball = d2 < kR2;
        const unsigned long long m = __ballot(in_ball);
        if (m) {
            if (in_ball) {
                const int slot = cnt + __popcll(m & ((1ull << lane) - 1ull));
                if (slot < kK) s_idx[w][slot] = p;
            }
            cnt += __popcll(m);          // wave-uniform
            if (cnt >= kK) break;        // uniform branch
        }
    }

    __syncthreads();   // all waves reach here exactly once; makes LDS writes visible

    if (lane < kK) {
        int v;
        if (cnt == 0)       v = 0;
        else if (lane < cnt) v = s_idx[w][lane];
        else                 v = s_idx[w][0];   // fill with first valid index
        idxs[(size_t)wave * kK + lane] = v;
    }
}

// ---------------------------------------------------------------------------
// Kernel 2: transpose features [B][64][Np] and t_embed [B][64][Np] into
// point-major pt[B][Np][128] (ch 0..63 = features, 64..127 = t_embed) so the
// gather reads fully-used contiguous 512B rows instead of scattered dwords.
// One block = one 64ch x 64pt tile of one source. Grid = B * (Np/64) * 2.
// ---------------------------------------------------------------------------
__global__ __launch_bounds__(256) void transpose_kernel(
    const float* __restrict__ feat,   // [B][64][Np]
    const float* __restrict__ temb,   // [B][64][Np]
    float* __restrict__ pt)           // [B][Np][128]
{
    __shared__ float tile[64][65];    // +1 pad: conflict-free both directions

    const int blk = blockIdx.x;
    const int src = blk & 1;               // 0: features, 1: t_embed
    const int pb  = (blk >> 1) & 127;      // point-tile index (Np/64 = 128)
    const int b   = blk >> 8;

    const float* in = (src ? temb : feat) + (size_t)b * 64 * kNp + pb * 64;

    // coalesced read: thread t -> p_local = t&63, ch = (t>>6) + 4*i
    {
        const int pl = threadIdx.x & 63;
        const int c0 = threadIdx.x >> 6;
        for (int i = 0; i < 16; ++i) {
            const int ch = c0 + i * 4;
            tile[ch][pl] = in[(size_t)ch * kNp + pl];
        }
    }
    __syncthreads();
    // coalesced write: thread t -> ch = t&63, p_local = (t>>6) + 4*i
    {
        const int ch = threadIdx.x & 63;
        const int p0 = threadIdx.x >> 6;
        float* out = pt + ((size_t)b * kNp + (size_t)pb * 64) * 128 + src * 64;
        for (int i = 0; i < 16; ++i) {
            const int p = p0 + i * 4;
            out[(size_t)p * 128 + ch] = tile[ch][p];
        }
    }
}

// ---------------------------------------------------------------------------
// Kernel 3: gather + write. One block per (b,q). Stage the 32 gathered
// point-rows (128 ch each) in LDS via fully-coalesced reads of pt, then emit
// channel-major output with the K=32 dimension contiguous (128B segments).
// ---------------------------------------------------------------------------
__global__ __launch_bounds__(256) void gather_kernel(
    const float* __restrict__ coords,   // [B][Np][3]
    const float* __restrict__ queries,  // [B][Nq][3]
    const int*   __restrict__ idxs,     // [B*Nq][K]
    const float* __restrict__ pt,       // [B][Np][128]
    float* __restrict__ out)            // gf [B][67][Nq][K] ++ te [B][64][Nq][K]
{
    const int bq = blockIdx.x;
    const int b  = bq >> 11;
    const int q  = bq & (kNq - 1);

    __shared__ int   s_idx[kK];
    __shared__ float tile[kK][129];   // [k][ch], pad 129 -> conflict-free col reads

    if (threadIdx.x < kK) s_idx[threadIdx.x] = idxs[(size_t)bq * kK + threadIdx.x];
    __syncthreads();

    // stage: 32 points x 128 ch; 256 threads = 2 point-rows per iteration
    {
        const int ch = threadIdx.x & 127;
        const int kk = threadIdx.x >> 7;   // 0..1
        for (int i = 0; i < 16; ++i) {
            const int k = i * 2 + kk;
            tile[k][ch] = pt[((size_t)b * kNp + s_idx[k]) * 128 + ch];
        }
    }
    __syncthreads();

    float* gf = out + ((size_t)b * 67 * kNq + q) * kK;   // channel stride = Nq*K
    const float* qp = queries + ((size_t)b * kNq + q) * 3;

    // channels 0..2: centered coords (coords[idx] - query)
    if (threadIdx.x < 96) {
        const int c = threadIdx.x >> 5;   // 0..2
        const int k = threadIdx.x & 31;
        const float v = coords[((size_t)b * kNp + s_idx[k]) * 3 + c] - qp[c];
        gf[(size_t)c * kNq * kK + k] = v;
    }
    // channels 3..66: features
    {
        const int k  = threadIdx.x & 31;
        const int c0 = threadIdx.x >> 5;  // 0..7
        for (int i = 0; i < 8; ++i) {
            const int c = c0 + i * 8;
            gf[(size_t)(3 + c) * kNq * kK + k] = tile[k][c];
        }
    }
    // t_embed output
    {
        float* te = out + (size_t)kB * 67 * kNq * kK + ((size_t)b * 64 * kNq + q) * kK;
        const int k  = threadIdx.x & 31;
        const int c0 = threadIdx.x >> 5;
        for (int i = 0; i < 8; ++i) {
            const int c = c0 + i * 8;
            te[(size_t)c * kNq * kK + k] = tile[k][64 + c];
        }
    }
}

// ---------------------------------------------------------------------------
extern "C" void kernel_launch(void* const* d_in, const int* in_sizes, int n_in,
                              void* d_out, int out_size, void* d_ws, size_t ws_size,
                              hipStream_t stream) {
    const float* coords  = (const float*)d_in[0];  // [B,Np,3]
    const float* feats   = (const float*)d_in[1];  // [B,64,Np]
    const float* temb    = (const float*)d_in[2];  // [B,64,Np]
    const float* queries = (const float*)d_in[3];  // [B,Nq,3]

    int*   idxs = (int*)d_ws;                                         // 1 MB
    float* pt   = (float*)((char*)d_ws + (size_t)kB * kNq * kK * 4);  // 16 MB

    ball_query_kernel<<<kB * kNq / 4, 256, 0, stream>>>(coords, queries, idxs);
    transpose_kernel<<<kB * (kNp / 64) * 2, 256, 0, stream>>>(feats, temb, pt);
    gather_kernel<<<kB * kNq, 256, 0, stream>>>(coords, queries, idxs, pt,
                                                (float*)d_out);
}

// Round 2
// 185.217 us; speedup vs baseline: 1.0998x; 1.0998x over previous
//
#include <hip/hip_runtime.h>

// Problem constants (fixed by setup_inputs)
constexpr int kB  = 4;
constexpr int kNp = 8192;
constexpr int kNq = 2048;
constexpr int kK  = 32;   // max samples per query
constexpr float kR2 = (float)(0.2 * 0.2);   // matches numpy f32(radius*radius)

// ---------------------------------------------------------------------------
// Kernel A: coords [B][Np][3] -> SoA cb3 [B][3][Np] so the ball-query scan
// does 3 fully-coalesced 256B loads per 64-point chunk instead of stride-12.
// ---------------------------------------------------------------------------
__global__ __launch_bounds__(256) void coords_soa_kernel(
    const float* __restrict__ coords, float* __restrict__ cb3)
{
    const int t = blockIdx.x * 256 + threadIdx.x;   // 0 .. B*Np-1
    const int b = t >> 13;                          // / Np
    const int p = t & (kNp - 1);
    const float x = coords[(size_t)t * 3 + 0];
    const float y = coords[(size_t)t * 3 + 1];
    const float z = coords[(size_t)t * 3 + 2];
    float* o = cb3 + (size_t)b * 3 * kNp;
    o[0 * kNp + p] = x;
    o[1 * kNp + p] = y;
    o[2 * kNp + p] = z;
}

// ---------------------------------------------------------------------------
// Kernel B: ball query. One wave per query. Scans points in groups of 4
// chunks (256 points) with one uniform early-exit check per group (12
// independent loads in flight -> 4x shorter latency-bound tail for
// full-scan queries). Ballot + prefix-popcount preserves exact
// first-K-in-index-order semantics. Also emits the 3 centered-coords output
// channels directly (it already holds the resolved indices).
// ---------------------------------------------------------------------------
__global__ __launch_bounds__(256) void ball_query_kernel(
    const float* __restrict__ cb3,      // [B][3][Np]
    const float* __restrict__ queries,  // [B][Nq][3]
    int* __restrict__ idxs,             // [B*Nq][K] (resolved, fill applied)
    float* __restrict__ out)            // full output tensor
{
    const int wave = (int)((blockIdx.x * blockDim.x + threadIdx.x) >> 6);
    const int lane = threadIdx.x & 63;
    const int w    = threadIdx.x >> 6;          // wave within block (0..3)
    const int b    = wave >> 11;                // / Nq
    const int q    = wave & (kNq - 1);

    const float qx = queries[(b * kNq + q) * 3 + 0];
    const float qy = queries[(b * kNq + q) * 3 + 1];
    const float qz = queries[(b * kNq + q) * 3 + 2];

    const float* __restrict__ cbx = cb3 + (size_t)b * 3 * kNp;
    const float* __restrict__ cby = cbx + kNp;
    const float* __restrict__ cbz = cby + kNp;

    __shared__ int s_idx[4][kK];   // per-wave private region; no barrier needed

    const unsigned long long lt = (1ull << lane) - 1ull;
    int cnt = 0;
    for (int base = 0; base < kNp; base += 256) {
#pragma unroll
        for (int j = 0; j < 4; ++j) {
            const int p = base + j * 64 + lane;
            const float cx = cbx[p];
            const float cy = cby[p];
            const float cz = cbz[p];
            // exact f32 per-op arithmetic (no fma contraction) to match numpy
            const float dx = __fsub_rn(qx, cx);
            const float dy = __fsub_rn(qy, cy);
            const float dz = __fsub_rn(qz, cz);
            const float d2 = __fadd_rn(
                __fadd_rn(__fmul_rn(dx, dx), __fmul_rn(dy, dy)),
                __fmul_rn(dz, dz));
            const bool in_ball = d2 < kR2;
            const unsigned long long m = __ballot(in_ball);
            if (in_ball) {
                const int slot = cnt + __popcll(m & lt);
                if (slot < kK) s_idx[w][slot] = p;
            }
            cnt += __popcll(m);              // wave-uniform
        }
        if (cnt >= kK) break;                // uniform branch, checked per 256
    }

    if (lane < kK) {
        int v;
        if (cnt == 0)        v = 0;
        else if (lane < cnt) v = s_idx[w][lane];
        else                 v = s_idx[w][0];       // fill with first valid
        idxs[(size_t)wave * kK + lane] = v;

        // centered-coords output channels 0..2 of grouped_features
        const int k = lane;
        float* gf = out + ((size_t)(b * 67) * kNq + q) * kK + k;
        gf[(size_t)0 * kNq * kK] = __fsub_rn(cbx[v], qx);
        gf[(size_t)1 * kNq * kK] = __fsub_rn(cby[v], qy);
        gf[(size_t)2 * kNq * kK] = __fsub_rn(cbz[v], qz);
    }
}

// ---------------------------------------------------------------------------
// Kernel C: scatter-free gather. One block per (b, source-channel): stage the
// 32KB channel row in LDS (coalesced float4), then out[c][q][k] = row[idx]
// with int4 idx loads + float4 stores (perfectly coalesced writes).
// Grid = B * 128 (64 feature + 64 t_embed channels).
// ---------------------------------------------------------------------------
__global__ __launch_bounds__(256) void gather_kernel(
    const float* __restrict__ feat,   // [B][64][Np]
    const float* __restrict__ temb,   // [B][64][Np]
    const int*   __restrict__ idxs,   // [B*Nq][K] resolved
    float* __restrict__ out)
{
    const int blk = blockIdx.x;        // 0 .. 511
    const int b   = blk >> 7;
    const int j   = blk & 127;         // 0..63 feat, 64..127 temb

    const float* src;
    float* dst;
    if (j < 64) {
        src = feat + ((size_t)b * 64 + j) * kNp;
        dst = out + (size_t)(b * 67 + 3 + j) * (kNq * kK);
    } else {
        src = temb + ((size_t)b * 64 + (j - 64)) * kNp;
        dst = out + (size_t)kB * 67 * kNq * kK
                  + (size_t)(b * 64 + (j - 64)) * (kNq * kK);
    }

    __shared__ float row[kNp];         // 32 KB
    {
        const float4* s4 = (const float4*)src;
        float4* r4 = (float4*)row;
#pragma unroll
        for (int i = 0; i < kNp / 4 / 256; ++i)     // 8 iters
            r4[i * 256 + threadIdx.x] = s4[i * 256 + threadIdx.x];
    }
    __syncthreads();

    const int4* id4 = (const int4*)(idxs + (size_t)b * kNq * kK);
    float4* d4 = (float4*)dst;
    constexpr int total4 = kNq * kK / 4;            // 16384
#pragma unroll 4
    for (int e = threadIdx.x; e < total4; e += 256) {
        const int4 id = id4[e];
        float4 v;
        v.x = row[id.x];
        v.y = row[id.y];
        v.z = row[id.z];
        v.w = row[id.w];
        d4[e] = v;
    }
}

// ---------------------------------------------------------------------------
extern "C" void kernel_launch(void* const* d_in, const int* in_sizes, int n_in,
                              void* d_out, int out_size, void* d_ws, size_t ws_size,
                              hipStream_t stream) {
    const float* coords  = (const float*)d_in[0];  // [B,Np,3]
    const float* feats   = (const float*)d_in[1];  // [B,64,Np]
    const float* temb    = (const float*)d_in[2];  // [B,64,Np]
    const float* queries = (const float*)d_in[3];  // [B,Nq,3]
    float* out = (float*)d_out;

    int*   idxs = (int*)d_ws;                                          // 1 MB
    float* cb3  = (float*)((char*)d_ws + (size_t)kB * kNq * kK * 4);   // 384 KB

    coords_soa_kernel<<<kB * kNp / 256, 256, 0, stream>>>(coords, cb3);
    ball_query_kernel<<<kB * kNq / 4, 256, 0, stream>>>(cb3, queries, idxs, out);
    gather_kernel<<<kB * 128, 256, 0, stream>>>(feats, temb, idxs, out);
}